// Round 5
// baseline (4014.730 us; speedup 1.0000x reference)
//
#include <hip/hip_runtime.h>
#include <hip/hip_bf16.h>
#include <cstdint>

#define NWIN   1024
#define NTOK   98
#define BIAS_N 9604   // 98*98

__device__ __forceinline__ float b2f(unsigned short u) {
  union { uint32_t i; float f; } v; v.i = ((uint32_t)u) << 16; return v.f;
}
__device__ __forceinline__ unsigned short f2b(float f) {  // RNE
  union { float f; uint32_t i; } v; v.f = f;
  uint32_t r = v.i + 0x7fffu + ((v.i >> 16) & 1u);
  return (unsigned short)(r >> 16);
}
// dtype-agnostic float-tensor load/store: f32 flag chooses interpretation
__device__ __forceinline__ float ldf(const void* p, size_t i, int f32) {
  return f32 ? ((const float*)p)[i] : b2f(((const unsigned short*)p)[i]);
}
__device__ __forceinline__ void stf(void* p, size_t i, int f32, float v) {
  if (f32) ((float*)p)[i] = v;
  else     ((unsigned short*)p)[i] = f2b(v);
}

// ---------------- K0: detect float-tensor storage format from x ----------------
// float32 N(0,1): uint32 exponent field in [112,134] (|v| ~ 1e-5..1e2) for ~all words.
// bf16-packed pairs: exponent field = (bf16exp<<1)|mantMSB ~ 250..255 -> out of range.
__global__ __launch_bounds__(256) void detect_kernel(const uint32_t* __restrict__ xw,
                                                     int* __restrict__ flag) {
  __shared__ int cnt;
  if (threadIdx.x == 0) cnt = 0;
  __syncthreads();
  uint32_t w = xw[threadIdx.x];
  int e = (w >> 23) & 0xFF;
  if (e >= 112 && e <= 134) atomicAdd(&cnt, 1);
  __syncthreads();
  if (threadIdx.x == 0) *flag = (cnt >= 128) ? 1 : 0;
}

// ---------------- K1: bias[h][i*98+j] = table[rel_idx[i,j]][h] (fp32) ----------------
__global__ __launch_bounds__(256) void bias_kernel(const int* __restrict__ rel_idx,
                                                   const void* __restrict__ tbl,
                                                   const int* __restrict__ flag,
                                                   float* __restrict__ bias) {
  const int f32 = *flag;
  int i = blockIdx.x * 256 + threadIdx.x;
  if (i >= 4 * BIAS_N) return;
  int h = i / BIAS_N, ij = i % BIAS_N;
  bias[i] = ldf(tbl, (size_t)rel_idx[ij] * 4 + h, f32);
}

// ---------------- K2: per-token LN1 (+roll gather) + QKV row; 384 threads/block ----------------
__global__ __launch_bounds__(384) void qkv_ln1_kernel(
    const void* __restrict__ x,
    const void* __restrict__ ln1g, const void* __restrict__ ln1b,
    const void* __restrict__ qkvw, const void* __restrict__ qkvb,
    const int* __restrict__ flag,
    unsigned short* __restrict__ qg, unsigned short* __restrict__ kg,
    unsigned short* __restrict__ vg) {
  __shared__ float xrow[128];
  __shared__ float red[128], red2[128];
  const int f32 = *flag;
  const int t = blockIdx.x, tid = threadIdx.x;
  const int win = t / NTOK, tn = t % NTOK;
  const int bb = win >> 8, r = win & 255;
  const int wd = r >> 6, r2 = r & 63, wh = r2 >> 3, ww = r2 & 7;
  const int td = tn / 49, r3 = tn % 49, th = r3 / 7, tw = r3 % 7;
  const int sd = (wd * 2 + td + 1) & 7;
  const int sh = (wh * 7 + th + 3) % 56;
  const int sw = (ww * 7 + tw + 3) % 56;
  const size_t src = ((((size_t)bb * 8 + sd) * 56 + sh) * 56 + sw) * 128;

  if (tid < 128) {
    float f = ldf(x, src + tid, f32);
    xrow[tid] = f; red[tid] = f; red2[tid] = f * f;
  }
  __syncthreads();
  for (int s = 64; s >= 1; s >>= 1) {
    if (tid < s) { red[tid] += red[tid + s]; red2[tid] += red2[tid + s]; }
    __syncthreads();
  }
  const float mu = red[0] * (1.0f / 128.0f);
  const float var = red2[0] * (1.0f / 128.0f) - mu * mu;
  const float rs = rsqrtf(var + 1e-5f);
  __syncthreads();
  if (tid < 128)
    xrow[tid] = (xrow[tid] - mu) * rs * ldf(ln1g, tid, f32) + ldf(ln1b, tid, f32);
  __syncthreads();

  // each thread: one of 384 qkv outputs for this token
  float acc = 0.f;
  for (int k = 0; k < 128; ++k) acc += xrow[k] * ldf(qkvw, (size_t)k * 384 + tid, f32);
  acc += ldf(qkvb, tid, f32);
  const int region = tid >> 7, cc = tid & 127, head = cc >> 5, d = cc & 31;
  if (region == 0) acc *= 0.17677669529663687f;  // hd^-0.5 (after bias, matches ref)
  unsigned short* dst = (region == 0 ? qg : (region == 1 ? kg : vg));
  dst[(((size_t)win * 4 + head) * NTOK + tn) * 32 + d] = f2b(acc);
}

// ---------------- K3: attention, block per (win, head); S matrix in LDS ----------------
__global__ __launch_bounds__(256) void attn_kernel(
    const unsigned short* __restrict__ qg, const unsigned short* __restrict__ kg,
    const unsigned short* __restrict__ vg, const float* __restrict__ bias,
    unsigned short* __restrict__ attnbuf) {
  __shared__ unsigned short qs[NTOK * 33], ks[NTOK * 33], vs[NTOK * 33];  // 19404 B
  __shared__ float S[NTOK * 99];                                          // 38808 B
  const int tid = threadIdx.x;
  const int win = blockIdx.x, h = blockIdx.y;
  const size_t base = (((size_t)win * 4 + h) * NTOK) * 32;
  for (int idx = tid; idx < NTOK * 32; idx += 256) {
    int row = idx >> 5, c = idx & 31;
    qs[row * 33 + c] = qg[base + idx];
    ks[row * 33 + c] = kg[base + idx];
    vs[row * 33 + c] = vg[base + idx];
  }
  __syncthreads();
  const float* bh = bias + h * BIAS_N;
  for (int idx = tid; idx < BIAS_N; idx += 256) {
    int i = idx / NTOK, j = idx % NTOK;
    float acc = 0.f;
    for (int d = 0; d < 32; ++d) acc += b2f(qs[i * 33 + d]) * b2f(ks[j * 33 + d]);
    S[i * 99 + j] = acc + bh[idx];
  }
  __syncthreads();
  if (tid < NTOK) {
    float mx = -3.0e38f;
    for (int j = 0; j < NTOK; ++j) mx = fmaxf(mx, S[tid * 99 + j]);
    float sum = 0.f;
    for (int j = 0; j < NTOK; ++j) {
      float e = __expf(S[tid * 99 + j] - mx);
      S[tid * 99 + j] = e; sum += e;
    }
    float inv = 1.0f / sum;
    for (int j = 0; j < NTOK; ++j) S[tid * 99 + j] *= inv;
  }
  __syncthreads();
  for (int idx = tid; idx < NTOK * 32; idx += 256) {
    int i = idx >> 5, d = idx & 31;
    float o = 0.f;
    for (int j = 0; j < NTOK; ++j) o += S[i * 99 + j] * b2f(vs[j * 33 + d]);
    attnbuf[((size_t)win * NTOK + i) * 128 + h * 32 + d] = f2b(o);
  }
}

// ---------------- K4: per-token proj + bias + residual scatter (reverse roll) ----------------
__global__ __launch_bounds__(128) void proj_kernel(
    const unsigned short* __restrict__ attnbuf,
    const void* __restrict__ projw, const void* __restrict__ projb,
    const void* __restrict__ x, const int* __restrict__ flag,
    void* __restrict__ out) {
  __shared__ float arow[128];
  const int f32 = *flag;
  const int t = blockIdx.x, tid = threadIdx.x;
  const int win = t / NTOK, tn = t % NTOK;
  const int bb = win >> 8, r = win & 255;
  const int wd = r >> 6, r2 = r & 63, wh = r2 >> 3, ww = r2 & 7;
  const int td = tn / 49, r3 = tn % 49, th = r3 / 7, tw = r3 % 7;
  const int sd = (wd * 2 + td + 1) & 7;
  const int sh = (wh * 7 + th + 3) % 56;
  const int sw = (ww * 7 + tw + 3) % 56;
  const size_t oidx = ((((size_t)bb * 8 + sd) * 56 + sh) * 56 + sw) * 128 + tid;

  arow[tid] = b2f(attnbuf[(size_t)t * 128 + tid]);
  __syncthreads();
  float acc = 0.f;
  for (int k = 0; k < 128; ++k) acc += arow[k] * ldf(projw, (size_t)k * 128 + tid, f32);
  acc += ldf(projb, tid, f32);
  stf(out, oidx, f32, acc + ldf(x, oidx, f32));
}

// ---------------- K5: per-token LN2 + MLP1 + GELU + MLP2 + residual (in-place) ----------------
__global__ __launch_bounds__(512) void mlp_kernel(
    const void* __restrict__ ln2g, const void* __restrict__ ln2b,
    const void* __restrict__ w1, const void* __restrict__ b1,
    const void* __restrict__ w2, const void* __restrict__ b2v,
    const int* __restrict__ flag, void* __restrict__ out) {
  __shared__ float xr[128], red[128], red2[128], hrow[512];
  const int f32 = *flag;
  const int t = blockIdx.x, tid = threadIdx.x;
  if (tid < 128) {
    float f = ldf(out, (size_t)t * 128 + tid, f32);
    xr[tid] = f; red[tid] = f; red2[tid] = f * f;
  }
  __syncthreads();
  for (int s = 64; s >= 1; s >>= 1) {
    if (tid < s) { red[tid] += red[tid + s]; red2[tid] += red2[tid + s]; }
    __syncthreads();
  }
  const float mu = red[0] * (1.0f / 128.0f);
  const float var = red2[0] * (1.0f / 128.0f) - mu * mu;
  const float rs = rsqrtf(var + 1e-5f);
  __syncthreads();
  if (tid < 128)
    xr[tid] = (xr[tid] - mu) * rs * ldf(ln2g, tid, f32) + ldf(ln2b, tid, f32);
  __syncthreads();

  // mlp1 + exact gelu: each of 512 threads computes one hidden unit
  float acc = 0.f;
  for (int k = 0; k < 128; ++k) acc += xr[k] * ldf(w1, (size_t)k * 512 + tid, f32);
  acc += ldf(b1, tid, f32);
  hrow[tid] = 0.5f * acc * (1.0f + erff(acc * 0.70710678118654752f));
  __syncthreads();

  // mlp2 + residual: first 128 threads each compute one output channel
  if (tid < 128) {
    float a2 = 0.f;
    for (int k = 0; k < 512; ++k) a2 += hrow[k] * ldf(w2, (size_t)k * 128 + tid, f32);
    a2 += ldf(b2v, tid, f32);
    const size_t oi = (size_t)t * 128 + tid;
    stf(out, oi, f32, a2 + ldf(out, oi, f32));
  }
}

// ---------------- host launch ----------------
extern "C" void kernel_launch(void* const* d_in, const int* in_sizes, int n_in,
                              void* d_out, int out_size, void* d_ws, size_t ws_size,
                              hipStream_t stream) {
  const void* x      = d_in[0];
  const int*  rel    = (const int*)d_in[1];
  const void* rpb    = d_in[2];
  const void* qkv_w  = d_in[3];
  const void* qkv_b  = d_in[4];
  const void* proj_w = d_in[5];
  const void* proj_b = d_in[6];
  const void* ln1_g  = d_in[7];
  const void* ln1_b  = d_in[8];
  const void* ln2_g  = d_in[9];
  const void* ln2_b  = d_in[10];
  const void* w1     = d_in[11];
  const void* b1     = d_in[12];
  const void* w2     = d_in[13];
  const void* b2     = d_in[14];

  char* ws = (char*)d_ws;
  unsigned short* qg   = (unsigned short*)(ws);               // 25,690,112 B
  unsigned short* kg   = (unsigned short*)(ws + 25690112);    // 25,690,112 B
  unsigned short* vg   = (unsigned short*)(ws + 51380224);    // 25,690,112 B
  unsigned short* attn = (unsigned short*)(ws + 77070336);    // 25,690,112 B
  float*          bias = (float*)(ws + 102760448);            //    153,664 B
  int*            flag = (int*)(ws + 102914112);              //          4 B

  detect_kernel<<<1, 256, 0, stream>>>((const uint32_t*)x, flag);
  bias_kernel<<<(4 * BIAS_N + 255) / 256, 256, 0, stream>>>(rel, rpb, flag, bias);
  qkv_ln1_kernel<<<NWIN * NTOK, 384, 0, stream>>>(x, ln1_g, ln1_b, qkv_w, qkv_b,
                                                  flag, qg, kg, vg);
  attn_kernel<<<dim3(NWIN, 4), 256, 0, stream>>>(qg, kg, vg, bias, attn);
  proj_kernel<<<NWIN * NTOK, 128, 0, stream>>>(attn, proj_w, proj_b, x, flag, d_out);
  mlp_kernel<<<NWIN * NTOK, 512, 0, stream>>>(ln2_g, ln2_b, w1, b1, w2, b2, flag, d_out);
}

// Round 6
// 966.623 us; speedup vs baseline: 4.1534x; 4.1534x over previous
//
#include <hip/hip_runtime.h>
#include <hip/hip_bf16.h>
#include <cstdint>

#define NWIN   1024
#define NTOK   98
#define BIAS_N 9604   // 98*98

typedef __attribute__((ext_vector_type(8))) short bf16x8;
typedef __attribute__((ext_vector_type(4))) float f32x4;

__device__ __forceinline__ float b2f(unsigned short u) {
  union { uint32_t i; float f; } v; v.i = ((uint32_t)u) << 16; return v.f;
}
__device__ __forceinline__ float b2f_lo(uint32_t u) {
  union { uint32_t i; float f; } v; v.i = u << 16; return v.f;
}
__device__ __forceinline__ float b2f_hi(uint32_t u) {
  union { uint32_t i; float f; } v; v.i = u & 0xffff0000u; return v.f;
}
__device__ __forceinline__ unsigned short f2b(float f) {  // RNE
  union { float f; uint32_t i; } v; v.f = f;
  uint32_t r = v.i + 0x7fffu + ((v.i >> 16) & 1u);
  return (unsigned short)(r >> 16);
}
// dtype-agnostic float-tensor access (f32 flag is wave-uniform)
__device__ __forceinline__ float ldf(const void* p, size_t i, int f32) {
  return f32 ? ((const float*)p)[i] : b2f(((const unsigned short*)p)[i]);
}
__device__ __forceinline__ void stf(void* p, size_t i, int f32, float v) {
  if (f32) ((float*)p)[i] = v;
  else     ((unsigned short*)p)[i] = f2b(v);
}
__device__ __forceinline__ float2 ldf2(const void* p, size_t i, int f32) {  // i even
  if (f32) { const float* q = (const float*)p + i; return make_float2(q[0], q[1]); }
  uint32_t u = *(const uint32_t*)((const unsigned short*)p + i);
  return make_float2(b2f_lo(u), b2f_hi(u));
}

// ws element offsets (bytes)
#define QG_OFF   0
#define KG_OFF   25690112
#define VG_OFF   51380224
#define AT_OFF   77070336
#define BIAS_OFF 102760448   // f32, 153664 B
#define WQ_OFF   102914112   // bf16 [384][128]
#define WP_OFF   103012416   // bf16 [128][128]
#define W1_OFF   103045184   // bf16 [512][128]
#define W2_OFF   103176256   // bf16 [128][512]
#define PAR_OFF  103307328   // f32 x 1664
#define FLAG_OFF 103313984
// param layout (float idx)
#define P_LN1G 0
#define P_LN1B 128
#define P_LN2G 256
#define P_LN2B 384
#define P_QKVB 512
#define P_PROJB 896
#define P_B1  1024
#define P_B2  1536

// ---------------- K0: detect float-tensor storage format from x ----------------
__global__ __launch_bounds__(256) void detect_kernel(const uint32_t* __restrict__ xw,
                                                     int* __restrict__ flag) {
  __shared__ int cnt;
  if (threadIdx.x == 0) cnt = 0;
  __syncthreads();
  uint32_t w = xw[threadIdx.x];
  int e = (w >> 23) & 0xFF;
  if (e >= 112 && e <= 134) atomicAdd(&cnt, 1);
  __syncthreads();
  if (threadIdx.x == 0) *flag = (cnt >= 128) ? 1 : 0;
}

// ---------------- K1: weight transpose->bf16 + param->f32 normalize ----------------
__global__ __launch_bounds__(256) void prep_kernel(
    const void* __restrict__ qkvw, const void* __restrict__ projw,
    const void* __restrict__ w1, const void* __restrict__ w2,
    const void* __restrict__ ln1g, const void* __restrict__ ln1b,
    const void* __restrict__ ln2g, const void* __restrict__ ln2b,
    const void* __restrict__ qkvb, const void* __restrict__ projb,
    const void* __restrict__ b1, const void* __restrict__ b2,
    const int* __restrict__ flag,
    unsigned short* __restrict__ wq_t, unsigned short* __restrict__ wp_t,
    unsigned short* __restrict__ w1_t, unsigned short* __restrict__ w2_t,
    float* __restrict__ par) {
  const int f32 = *flag;
  int idx = blockIdx.x * 256 + threadIdx.x;
  if (idx < 49152) {                       // wq_t[n][k] = qkv_w[k][n], 384x128
    int n = idx >> 7, k = idx & 127;
    wq_t[idx] = f2b(ldf(qkvw, (size_t)k * 384 + n, f32));
  } else if ((idx -= 49152) < 16384) {     // wp_t[n][k] = proj_w[k][n], 128x128
    int n = idx >> 7, k = idx & 127;
    wp_t[idx] = f2b(ldf(projw, (size_t)k * 128 + n, f32));
  } else if ((idx -= 16384) < 65536) {     // w1_t[n][k] = w1[k][n], 512x128
    int n = idx >> 7, k = idx & 127;
    w1_t[idx] = f2b(ldf(w1, (size_t)k * 512 + n, f32));
  } else if ((idx -= 65536) < 65536) {     // w2_t[n][k] = w2[k][n], 128x512
    int n = idx >> 9, k = idx & 511;
    w2_t[idx] = f2b(ldf(w2, (size_t)k * 128 + n, f32));
  } else if ((idx -= 65536) < 1664) {      // params -> f32
    float v;
    if      (idx < 128)  v = ldf(ln1g, idx, f32);
    else if (idx < 256)  v = ldf(ln1b, idx - 128, f32);
    else if (idx < 384)  v = ldf(ln2g, idx - 256, f32);
    else if (idx < 512)  v = ldf(ln2b, idx - 384, f32);
    else if (idx < 896)  v = ldf(qkvb, idx - 512, f32);
    else if (idx < 1024) v = ldf(projb, idx - 896, f32);
    else if (idx < 1536) v = ldf(b1, idx - 1024, f32);
    else                 v = ldf(b2, idx - 1536, f32);
    par[idx] = v;
  }
}

// ---------------- K2: bias[h][i*98+j] = table[rel_idx[i,j]][h] (fp32) ----------------
__global__ __launch_bounds__(256) void bias_kernel(const int* __restrict__ rel_idx,
                                                   const void* __restrict__ tbl,
                                                   const int* __restrict__ flag,
                                                   float* __restrict__ bias) {
  const int f32 = *flag;
  int i = blockIdx.x * 256 + threadIdx.x;
  if (i >= 4 * BIAS_N) return;
  int h = i / BIAS_N, ij = i % BIAS_N;
  bias[i] = ldf(tbl, (size_t)rel_idx[ij] * 4 + h, f32);
}

// ---------------- K3: per-window LN1+gather + QKV MFMA -> q/k/v [win][h][98][32] bf16 ----------------
__global__ __launch_bounds__(256) void qkv_win_kernel(
    const void* __restrict__ x, const int* __restrict__ flag,
    const unsigned short* __restrict__ wq_t, const float* __restrict__ par,
    unsigned short* __restrict__ qg, unsigned short* __restrict__ kg,
    unsigned short* __restrict__ vg) {
  __shared__ unsigned short lnx[112 * 136];   // 30464 B
  const int f32 = *flag;
  const int tid = threadIdx.x, wave = tid >> 6, lane = tid & 63;
  const int quad = lane >> 4, lcol = lane & 15;
  const int win = blockIdx.x;
  const int bb = win >> 8, r = win & 255;
  const int wd = r >> 6, r2 = r & 63, wh = r2 >> 3, ww = r2 & 7;

  for (int t = wave; t < NTOK; t += 4) {
    int td = t / 49, r3 = t % 49, th = r3 / 7, tw = r3 % 7;
    int sd = (wd * 2 + td + 1) & 7;
    int sh = (wh * 7 + th + 3) % 56;
    int sw = (ww * 7 + tw + 3) % 56;
    size_t src = ((((size_t)bb * 8 + sd) * 56 + sh) * 56 + sw) * 128;
    int c0 = lane * 2;
    float2 f = ldf2(x, src + c0, f32);
    float s = f.x + f.y, ss = f.x * f.x + f.y * f.y;
#pragma unroll
    for (int off = 32; off >= 1; off >>= 1) { s += __shfl_xor(s, off); ss += __shfl_xor(ss, off); }
    float mu = s * (1.0f / 128.0f);
    float var = ss * (1.0f / 128.0f) - mu * mu;
    float rs = rsqrtf(var + 1e-5f);
    float y0 = (f.x - mu) * rs * par[P_LN1G + c0] + par[P_LN1B + c0];
    float y1 = (f.y - mu) * rs * par[P_LN1G + c0 + 1] + par[P_LN1B + c0 + 1];
    *(uint32_t*)(lnx + t * 136 + c0) = (uint32_t)f2b(y0) | ((uint32_t)f2b(y1) << 16);
  }
  for (int i = tid; i < 14 * 68; i += 256) {   // zero pad rows 98..111
    int rr = i / 68, c = i % 68;
    *(uint32_t*)(lnx + (98 + rr) * 136 + c * 2) = 0u;
  }
  __syncthreads();

  for (int p = 0; p < 6; ++p) {
    const int n = p * 64 + wave * 16 + lcol;
    bf16x8 bfr[4];
#pragma unroll
    for (int ks = 0; ks < 4; ++ks)
      bfr[ks] = *(const bf16x8*)(wq_t + (size_t)n * 128 + ks * 32 + quad * 8);
    const int region = n >> 7, cc = n & 127, head = cc >> 5, d = cc & 31;
    unsigned short* dst = (region == 0 ? qg : (region == 1 ? kg : vg)) +
                          (((size_t)win * 4 + head) * NTOK) * 32 + d;
    const float bc = par[P_QKVB + n];
    const float scale = region == 0 ? 0.17677669529663687f : 1.0f;
    for (int mt = 0; mt < 7; ++mt) {
      f32x4 acc = (f32x4){0.f, 0.f, 0.f, 0.f};
#pragma unroll
      for (int ks = 0; ks < 4; ++ks) {
        bf16x8 a = *(const bf16x8*)(lnx + (mt * 16 + lcol) * 136 + ks * 32 + quad * 8);
        acc = __builtin_amdgcn_mfma_f32_16x16x32_bf16(a, bfr[ks], acc, 0, 0, 0);
      }
#pragma unroll
      for (int rr = 0; rr < 4; ++rr) {
        int m = mt * 16 + quad * 4 + rr;
        if (m < NTOK) dst[m * 32] = f2b((acc[rr] + bc) * scale);
      }
    }
  }
}

// ---------------- K4: attention (validated round-5 kernel, unchanged) ----------------
__global__ __launch_bounds__(256) void attn_kernel(
    const unsigned short* __restrict__ qg, const unsigned short* __restrict__ kg,
    const unsigned short* __restrict__ vg, const float* __restrict__ bias,
    unsigned short* __restrict__ attnbuf) {
  __shared__ unsigned short qs[NTOK * 33], ks[NTOK * 33], vs[NTOK * 33];
  __shared__ float S[NTOK * 99];
  const int tid = threadIdx.x;
  const int win = blockIdx.x, h = blockIdx.y;
  const size_t base = (((size_t)win * 4 + h) * NTOK) * 32;
  for (int idx = tid; idx < NTOK * 32; idx += 256) {
    int row = idx >> 5, c = idx & 31;
    qs[row * 33 + c] = qg[base + idx];
    ks[row * 33 + c] = kg[base + idx];
    vs[row * 33 + c] = vg[base + idx];
  }
  __syncthreads();
  const float* bh = bias + h * BIAS_N;
  for (int idx = tid; idx < BIAS_N; idx += 256) {
    int i = idx / NTOK, j = idx % NTOK;
    float acc = 0.f;
    for (int d = 0; d < 32; ++d) acc += b2f(qs[i * 33 + d]) * b2f(ks[j * 33 + d]);
    S[i * 99 + j] = acc + bh[idx];
  }
  __syncthreads();
  if (tid < NTOK) {
    float mx = -3.0e38f;
    for (int j = 0; j < NTOK; ++j) mx = fmaxf(mx, S[tid * 99 + j]);
    float sum = 0.f;
    for (int j = 0; j < NTOK; ++j) {
      float e = __expf(S[tid * 99 + j] - mx);
      S[tid * 99 + j] = e; sum += e;
    }
    float inv = 1.0f / sum;
    for (int j = 0; j < NTOK; ++j) S[tid * 99 + j] *= inv;
  }
  __syncthreads();
  for (int idx = tid; idx < NTOK * 32; idx += 256) {
    int i = idx >> 5, d = idx & 31;
    float o = 0.f;
    for (int j = 0; j < NTOK; ++j) o += S[i * 99 + j] * b2f(vs[j * 33 + d]);
    attnbuf[((size_t)win * NTOK + i) * 128 + h * 32 + d] = f2b(o);
  }
}

// ---------------- K5: per-window proj MFMA + bias + residual scatter ----------------
__global__ __launch_bounds__(256) void proj_kernel(
    const unsigned short* __restrict__ attnbuf,
    const unsigned short* __restrict__ wp_t, const float* __restrict__ par,
    const void* __restrict__ x, const int* __restrict__ flag,
    void* __restrict__ out) {
  const int f32 = *flag;
  const int tid = threadIdx.x, wave = tid >> 6, lane = tid & 63;
  const int quad = lane >> 4, lcol = lane & 15;
  const int win = blockIdx.x;
  const int bb = win >> 8, r = win & 255;
  const int wd = r >> 6, r2 = r & 63, wh = r2 >> 3, ww = r2 & 7;

  for (int p = 0; p < 2; ++p) {
    const int n = p * 64 + wave * 16 + lcol;
    bf16x8 bfr[4];
#pragma unroll
    for (int ks = 0; ks < 4; ++ks)
      bfr[ks] = *(const bf16x8*)(wp_t + (size_t)n * 128 + ks * 32 + quad * 8);
    const float bc = par[P_PROJB + n];
    for (int mt = 0; mt < 7; ++mt) {
      const int arow = min(mt * 16 + lcol, NTOK - 1);   // clamp pad rows
      f32x4 acc = (f32x4){0.f, 0.f, 0.f, 0.f};
#pragma unroll
      for (int ks = 0; ks < 4; ++ks) {
        bf16x8 a = *(const bf16x8*)(attnbuf + ((size_t)win * NTOK + arow) * 128 +
                                    ks * 32 + quad * 8);
        acc = __builtin_amdgcn_mfma_f32_16x16x32_bf16(a, bfr[ks], acc, 0, 0, 0);
      }
#pragma unroll
      for (int rr = 0; rr < 4; ++rr) {
        int m = mt * 16 + quad * 4 + rr;
        if (m < NTOK) {
          int td = m / 49, r3 = m % 49, th = r3 / 7, tw = r3 % 7;
          int sd = (wd * 2 + td + 1) & 7;
          int sh = (wh * 7 + th + 3) % 56;
          int sw = (ww * 7 + tw + 3) % 56;
          size_t oidx = ((((size_t)bb * 8 + sd) * 56 + sh) * 56 + sw) * 128 + n;
          stf(out, oidx, f32, acc[rr] + bc + ldf(x, oidx, f32));
        }
      }
    }
  }
}

// ---------------- K6: LN2 + MLP1(gelu) + MLP2 + residual, 32-token tiles, MFMA ----------------
__global__ __launch_bounds__(256) void mlp_kernel(
    const unsigned short* __restrict__ w1_t, const unsigned short* __restrict__ w2_t,
    const float* __restrict__ par, const int* __restrict__ flag,
    void* __restrict__ out) {
  __shared__ unsigned short lnt[32 * 136];   //  8704 B
  __shared__ unsigned short hb [32 * 520];   // 33280 B  (total 41984 B)
  const int f32 = *flag;
  const int tid = threadIdx.x, wave = tid >> 6, lane = tid & 63;
  const int quad = lane >> 4, lcol = lane & 15;
  const int m0 = blockIdx.x * 32;

  for (int t = wave; t < 32; t += 4) {
    int c0 = lane * 2;
    float2 f = ldf2(out, (size_t)(m0 + t) * 128 + c0, f32);
    float s = f.x + f.y, ss = f.x * f.x + f.y * f.y;
#pragma unroll
    for (int off = 32; off >= 1; off >>= 1) { s += __shfl_xor(s, off); ss += __shfl_xor(ss, off); }
    float mu = s * (1.0f / 128.0f);
    float var = ss * (1.0f / 128.0f) - mu * mu;
    float rs = rsqrtf(var + 1e-5f);
    float y0 = (f.x - mu) * rs * par[P_LN2G + c0] + par[P_LN2B + c0];
    float y1 = (f.y - mu) * rs * par[P_LN2G + c0 + 1] + par[P_LN2B + c0 + 1];
    *(uint32_t*)(lnt + t * 136 + c0) = (uint32_t)f2b(y0) | ((uint32_t)f2b(y1) << 16);
  }
  __syncthreads();

  // mlp1 + exact gelu -> hb[32][512] (stride 520)
  for (int p = 0; p < 8; ++p) {
    const int n = p * 64 + wave * 16 + lcol;
    bf16x8 bfr[4];
#pragma unroll
    for (int ks = 0; ks < 4; ++ks)
      bfr[ks] = *(const bf16x8*)(w1_t + (size_t)n * 128 + ks * 32 + quad * 8);
    const float bc = par[P_B1 + n];
#pragma unroll
    for (int mt = 0; mt < 2; ++mt) {
      f32x4 acc = (f32x4){0.f, 0.f, 0.f, 0.f};
#pragma unroll
      for (int ks = 0; ks < 4; ++ks) {
        bf16x8 a = *(const bf16x8*)(lnt + (mt * 16 + lcol) * 136 + ks * 32 + quad * 8);
        acc = __builtin_amdgcn_mfma_f32_16x16x32_bf16(a, bfr[ks], acc, 0, 0, 0);
      }
#pragma unroll
      for (int rr = 0; rr < 4; ++rr) {
        int m = mt * 16 + quad * 4 + rr;
        float v = acc[rr] + bc;
        v = 0.5f * v * (1.0f + erff(v * 0.70710678118654752f));
        hb[m * 520 + n] = f2b(v);
      }
    }
  }
  __syncthreads();

  // mlp2: K=512 over hb
  f32x4 acc2[2][2];
#pragma unroll
  for (int a = 0; a < 2; ++a)
#pragma unroll
    for (int b = 0; b < 2; ++b) acc2[a][b] = (f32x4){0.f, 0.f, 0.f, 0.f};
#pragma unroll
  for (int np = 0; np < 2; ++np) {
    const int n = np * 64 + wave * 16 + lcol;
    for (int kp = 0; kp < 4; ++kp) {
      bf16x8 bfr[4];
#pragma unroll
      for (int ks = 0; ks < 4; ++ks)
        bfr[ks] = *(const bf16x8*)(w2_t + (size_t)n * 512 + kp * 128 + ks * 32 + quad * 8);
#pragma unroll
      for (int mt = 0; mt < 2; ++mt) {
#pragma unroll
        for (int ks = 0; ks < 4; ++ks) {
          bf16x8 a = *(const bf16x8*)(hb + (mt * 16 + lcol) * 520 + kp * 128 +
                                      ks * 32 + quad * 8);
          acc2[np][mt] = __builtin_amdgcn_mfma_f32_16x16x32_bf16(a, bfr[ks], acc2[np][mt], 0, 0, 0);
        }
      }
    }
  }
#pragma unroll
  for (int np = 0; np < 2; ++np) {
    const int n = np * 64 + wave * 16 + lcol;
    const float bc = par[P_B2 + n];
#pragma unroll
    for (int mt = 0; mt < 2; ++mt) {
#pragma unroll
      for (int rr = 0; rr < 4; ++rr) {
        size_t oi = (size_t)(m0 + mt * 16 + quad * 4 + rr) * 128 + n;
        stf(out, oi, f32, acc2[np][mt][rr] + bc + ldf(out, oi, f32));
      }
    }
  }
}

// ---------------- host launch ----------------
extern "C" void kernel_launch(void* const* d_in, const int* in_sizes, int n_in,
                              void* d_out, int out_size, void* d_ws, size_t ws_size,
                              hipStream_t stream) {
  const void* x      = d_in[0];
  const int*  rel    = (const int*)d_in[1];
  const void* rpb    = d_in[2];
  const void* qkv_w  = d_in[3];
  const void* qkv_b  = d_in[4];
  const void* proj_w = d_in[5];
  const void* proj_b = d_in[6];
  const void* ln1_g  = d_in[7];
  const void* ln1_b  = d_in[8];
  const void* ln2_g  = d_in[9];
  const void* ln2_b  = d_in[10];
  const void* w1     = d_in[11];
  const void* b1     = d_in[12];
  const void* w2     = d_in[13];
  const void* b2     = d_in[14];

  char* ws = (char*)d_ws;
  unsigned short* qg   = (unsigned short*)(ws + QG_OFF);
  unsigned short* kg   = (unsigned short*)(ws + KG_OFF);
  unsigned short* vg   = (unsigned short*)(ws + VG_OFF);
  unsigned short* attn = (unsigned short*)(ws + AT_OFF);
  float*          bias = (float*)(ws + BIAS_OFF);
  unsigned short* wq_t = (unsigned short*)(ws + WQ_OFF);
  unsigned short* wp_t = (unsigned short*)(ws + WP_OFF);
  unsigned short* w1_t = (unsigned short*)(ws + W1_OFF);
  unsigned short* w2_t = (unsigned short*)(ws + W2_OFF);
  float*          par  = (float*)(ws + PAR_OFF);
  int*            flag = (int*)(ws + FLAG_OFF);

  detect_kernel<<<1, 256, 0, stream>>>((const uint32_t*)x, flag);
  prep_kernel<<<775, 256, 0, stream>>>(qkv_w, proj_w, w1, w2, ln1_g, ln1_b, ln2_g,
                                       ln2_b, qkv_b, proj_b, b1, b2, flag,
                                       wq_t, wp_t, w1_t, w2_t, par);
  bias_kernel<<<(4 * BIAS_N + 255) / 256, 256, 0, stream>>>(rel, rpb, flag, bias);
  qkv_win_kernel<<<NWIN, 256, 0, stream>>>(x, flag, wq_t, par, qg, kg, vg);
  attn_kernel<<<dim3(NWIN, 4), 256, 0, stream>>>(qg, kg, vg, bias, attn);
  proj_kernel<<<NWIN, 256, 0, stream>>>(attn, wp_t, par, x, flag, d_out);
  mlp_kernel<<<100352 / 32, 256, 0, stream>>>(w1_t, w2_t, par, flag, d_out);
}

// Round 7
// 477.857 us; speedup vs baseline: 8.4015x; 2.0228x over previous
//
#include <hip/hip_runtime.h>
#include <hip/hip_bf16.h>
#include <cstdint>

#define NWIN   1024
#define NTOK   98
#define BIAS_N 9604   // 98*98

typedef __attribute__((ext_vector_type(8))) short bf16x8;
typedef __attribute__((ext_vector_type(4))) float f32x4;

__device__ __forceinline__ float b2f(unsigned short u) {
  union { uint32_t i; float f; } v; v.i = ((uint32_t)u) << 16; return v.f;
}
__device__ __forceinline__ float b2f_lo(uint32_t u) {
  union { uint32_t i; float f; } v; v.i = u << 16; return v.f;
}
__device__ __forceinline__ float b2f_hi(uint32_t u) {
  union { uint32_t i; float f; } v; v.i = u & 0xffff0000u; return v.f;
}
__device__ __forceinline__ unsigned short f2b(float f) {  // RNE
  union { float f; uint32_t i; } v; v.f = f;
  uint32_t r = v.i + 0x7fffu + ((v.i >> 16) & 1u);
  return (unsigned short)(r >> 16);
}
__device__ __forceinline__ float ldf(const void* p, size_t i, int f32) {
  return f32 ? ((const float*)p)[i] : b2f(((const unsigned short*)p)[i]);
}
__device__ __forceinline__ void stf(void* p, size_t i, int f32, float v) {
  if (f32) ((float*)p)[i] = v;
  else     ((unsigned short*)p)[i] = f2b(v);
}
__device__ __forceinline__ float2 ldf2(const void* p, size_t i, int f32) {  // i even
  if (f32) { const float* q = (const float*)p + i; return make_float2(q[0], q[1]); }
  uint32_t u = *(const uint32_t*)((const unsigned short*)p + i);
  return make_float2(b2f_lo(u), b2f_hi(u));
}

// ws offsets (bytes)
#define QG_OFF   0
#define KG_OFF   25690112
#define VG_OFF   51380224
#define BIAS_OFF 77070336    // f32, 153664 B
#define WQ_OFF   77224000    // bf16 [384][128]
#define WP_OFF   77322304    // bf16 [128][128]
#define W1_OFF   77355072    // bf16 [512][128]
#define W2_OFF   77486144    // bf16 [128][512]
#define PAR_OFF  77617216    // f32 x 1664
#define FLAG_OFF 77623872
// param layout (float idx)
#define P_LN1G 0
#define P_LN1B 128
#define P_LN2G 256
#define P_LN2B 384
#define P_QKVB 512
#define P_PROJB 896
#define P_B1  1024
#define P_B2  1536

// ---------------- K0: detect float-tensor storage format ----------------
__global__ __launch_bounds__(256) void detect_kernel(const uint32_t* __restrict__ xw,
                                                     int* __restrict__ flag) {
  __shared__ int cnt;
  if (threadIdx.x == 0) cnt = 0;
  __syncthreads();
  uint32_t w = xw[threadIdx.x];
  int e = (w >> 23) & 0xFF;
  if (e >= 112 && e <= 134) atomicAdd(&cnt, 1);
  __syncthreads();
  if (threadIdx.x == 0) *flag = (cnt >= 128) ? 1 : 0;
}

// ---------------- K1: weight transpose->bf16 + param->f32 ----------------
__global__ __launch_bounds__(256) void prep_kernel(
    const void* __restrict__ qkvw, const void* __restrict__ projw,
    const void* __restrict__ w1, const void* __restrict__ w2,
    const void* __restrict__ ln1g, const void* __restrict__ ln1b,
    const void* __restrict__ ln2g, const void* __restrict__ ln2b,
    const void* __restrict__ qkvb, const void* __restrict__ projb,
    const void* __restrict__ b1, const void* __restrict__ b2,
    const int* __restrict__ flag,
    unsigned short* __restrict__ wq_t, unsigned short* __restrict__ wp_t,
    unsigned short* __restrict__ w1_t, unsigned short* __restrict__ w2_t,
    float* __restrict__ par) {
  const int f32 = *flag;
  int idx = blockIdx.x * 256 + threadIdx.x;
  if (idx < 49152) {
    int n = idx >> 7, k = idx & 127;
    wq_t[idx] = f2b(ldf(qkvw, (size_t)k * 384 + n, f32));
  } else if ((idx -= 49152) < 16384) {
    int n = idx >> 7, k = idx & 127;
    wp_t[idx] = f2b(ldf(projw, (size_t)k * 128 + n, f32));
  } else if ((idx -= 16384) < 65536) {
    int n = idx >> 7, k = idx & 127;
    w1_t[idx] = f2b(ldf(w1, (size_t)k * 512 + n, f32));
  } else if ((idx -= 65536) < 65536) {
    int n = idx >> 9, k = idx & 511;
    w2_t[idx] = f2b(ldf(w2, (size_t)k * 128 + n, f32));
  } else if ((idx -= 65536) < 1664) {
    float v;
    if      (idx < 128)  v = ldf(ln1g, idx, f32);
    else if (idx < 256)  v = ldf(ln1b, idx - 128, f32);
    else if (idx < 384)  v = ldf(ln2g, idx - 256, f32);
    else if (idx < 512)  v = ldf(ln2b, idx - 384, f32);
    else if (idx < 896)  v = ldf(qkvb, idx - 512, f32);
    else if (idx < 1024) v = ldf(projb, idx - 896, f32);
    else if (idx < 1536) v = ldf(b1, idx - 1024, f32);
    else                 v = ldf(b2, idx - 1536, f32);
    par[idx] = v;
  }
}

// ---------------- K2: bias[h][i*98+j] = table[rel_idx[i,j]][h] ----------------
__global__ __launch_bounds__(256) void bias_kernel(const int* __restrict__ rel_idx,
                                                   const void* __restrict__ tbl,
                                                   const int* __restrict__ flag,
                                                   float* __restrict__ bias) {
  const int f32 = *flag;
  int i = blockIdx.x * 256 + threadIdx.x;
  if (i >= 4 * BIAS_N) return;
  int h = i / BIAS_N, ij = i % BIAS_N;
  bias[i] = ldf(tbl, (size_t)rel_idx[ij] * 4 + h, f32);
}

// ---------------- K3: per-window LN1+gather + QKV MFMA (unchanged from r6) ----------------
__global__ __launch_bounds__(256) void qkv_win_kernel(
    const void* __restrict__ x, const int* __restrict__ flag,
    const unsigned short* __restrict__ wq_t, const float* __restrict__ par,
    unsigned short* __restrict__ qg, unsigned short* __restrict__ kg,
    unsigned short* __restrict__ vg) {
  __shared__ unsigned short lnx[112 * 136];
  const int f32 = *flag;
  const int tid = threadIdx.x, wave = tid >> 6, lane = tid & 63;
  const int quad = lane >> 4, lcol = lane & 15;
  const int win = blockIdx.x;
  const int bb = win >> 8, r = win & 255;
  const int wd = r >> 6, r2 = r & 63, wh = r2 >> 3, ww = r2 & 7;

  for (int t = wave; t < NTOK; t += 4) {
    int td = t / 49, r3 = t % 49, th = r3 / 7, tw = r3 % 7;
    int sd = (wd * 2 + td + 1) & 7;
    int sh = (wh * 7 + th + 3) % 56;
    int sw = (ww * 7 + tw + 3) % 56;
    size_t src = ((((size_t)bb * 8 + sd) * 56 + sh) * 56 + sw) * 128;
    int c0 = lane * 2;
    float2 f = ldf2(x, src + c0, f32);
    float s = f.x + f.y, ss = f.x * f.x + f.y * f.y;
#pragma unroll
    for (int off = 32; off >= 1; off >>= 1) { s += __shfl_xor(s, off); ss += __shfl_xor(ss, off); }
    float mu = s * (1.0f / 128.0f);
    float var = ss * (1.0f / 128.0f) - mu * mu;
    float rs = rsqrtf(var + 1e-5f);
    float y0 = (f.x - mu) * rs * par[P_LN1G + c0] + par[P_LN1B + c0];
    float y1 = (f.y - mu) * rs * par[P_LN1G + c0 + 1] + par[P_LN1B + c0 + 1];
    *(uint32_t*)(lnx + t * 136 + c0) = (uint32_t)f2b(y0) | ((uint32_t)f2b(y1) << 16);
  }
  for (int i = tid; i < 14 * 68; i += 256) {
    int rr = i / 68, c = i % 68;
    *(uint32_t*)(lnx + (98 + rr) * 136 + c * 2) = 0u;
  }
  __syncthreads();

  for (int p = 0; p < 6; ++p) {
    const int n = p * 64 + wave * 16 + lcol;
    bf16x8 bfr[4];
#pragma unroll
    for (int ks = 0; ks < 4; ++ks)
      bfr[ks] = *(const bf16x8*)(wq_t + (size_t)n * 128 + ks * 32 + quad * 8);
    const int region = n >> 7, cc = n & 127, head = cc >> 5, d = cc & 31;
    unsigned short* dst = (region == 0 ? qg : (region == 1 ? kg : vg)) +
                          (((size_t)win * 4 + head) * NTOK) * 32 + d;
    const float bc = par[P_QKVB + n];
    const float scale = region == 0 ? 0.17677669529663687f : 1.0f;
    for (int mt = 0; mt < 7; ++mt) {
      f32x4 acc = (f32x4){0.f, 0.f, 0.f, 0.f};
#pragma unroll
      for (int ks = 0; ks < 4; ++ks) {
        bf16x8 a = *(const bf16x8*)(lnx + (mt * 16 + lcol) * 136 + ks * 32 + quad * 8);
        acc = __builtin_amdgcn_mfma_f32_16x16x32_bf16(a, bfr[ks], acc, 0, 0, 0);
      }
#pragma unroll
      for (int rr = 0; rr < 4; ++rr) {
        int m = mt * 16 + quad * 4 + rr;
        if (m < NTOK) dst[m * 32] = f2b((acc[rr] + bc) * scale);
      }
    }
  }
}

// ---------------- K4: fused MFMA attention + proj + residual, 1 block/window ----------------
// wave = head. QK^T: A=Q rows, B=K rows (direct global frags). Softmax in registers
// (reg-max over 7 N-tiles + shfl_xor over 16-lane col group). P -> LDS (A-layout
// round-trip), V^T in LDS for B-operand. Attn-out -> LDS (overlay) -> proj MFMA
// with B-frags from wp_t (L2-hot) -> residual scatter with reverse roll.
__global__ __launch_bounds__(256) void attn_fused_kernel(
    const unsigned short* __restrict__ qg, const unsigned short* __restrict__ kg,
    const unsigned short* __restrict__ vg, const float* __restrict__ bias,
    const unsigned short* __restrict__ wp_t, const float* __restrict__ par,
    const void* __restrict__ x, const int* __restrict__ flag,
    void* __restrict__ out) {
  __shared__ unsigned short smem[26112];   // 52224 B: vt[4][32*136] | pl[4][16*136]; olds overlays
  const int f32 = *flag;
  const int tid = threadIdx.x, wave = tid >> 6, lane = tid & 63;
  const int quad = lane >> 4, lcol = lane & 15;
  const int win = blockIdx.x, h = wave;
  const size_t hb = (((size_t)win * 4 + h) * NTOK) * 32;

  unsigned short* vth = smem + h * (32 * 136);
  unsigned short* plh = smem + 17408 + h * (16 * 136);

  // ---- stage V^T (vt[d][j] = V[j][d]), zero pads; zero pl cols 112..127 ----
  {
    const uint32_t* vsrc = (const uint32_t*)(vg + hb);
    for (int idx = lane; idx < NTOK * 16; idx += 64) {
      int j = idx >> 4, dp = idx & 15;
      uint32_t u = vsrc[idx];
      vth[(2 * dp) * 136 + j]     = (unsigned short)(u & 0xffffu);
      vth[(2 * dp + 1) * 136 + j] = (unsigned short)(u >> 16);
    }
    for (int idx = lane; idx < 32 * 30; idx += 64) {
      int d = idx / 30, c = 98 + idx % 30;
      vth[d * 136 + c] = 0;
    }
    for (int idx = lane; idx < 16 * 16; idx += 64) {
      int rr = idx >> 4, c = 112 + (idx & 15);
      plh[rr * 136 + c] = 0;
    }
  }
  __syncthreads();

  // ---- Q/K fragments direct from global (rows clamped at 97; pad rows discarded) ----
  bf16x8 aq[7], bk[7];
#pragma unroll
  for (int t = 0; t < 7; ++t) {
    int row = min(t * 16 + lcol, NTOK - 1);
    aq[t] = *(const bf16x8*)(qg + hb + (size_t)row * 32 + quad * 8);
    bk[t] = *(const bf16x8*)(kg + hb + (size_t)row * 32 + quad * 8);
  }

  const float* bh = bias + h * BIAS_N;
  f32x4 o[7][2];
  for (int mt = 0; mt < 7; ++mt) {
    // scores S[i][j], i = mt*16+quad*4+r, j = nt*16+lcol
    f32x4 s[7];
#pragma unroll
    for (int nt = 0; nt < 7; ++nt)
      s[nt] = __builtin_amdgcn_mfma_f32_16x16x32_bf16(aq[mt], bk[nt],
                                                      (f32x4){0.f, 0.f, 0.f, 0.f}, 0, 0, 0);
    const int ib = mt * 16 + quad * 4;
#pragma unroll
    for (int nt = 0; nt < 7; ++nt) {
      int j = nt * 16 + lcol;
      bool jv = j < NTOK;
#pragma unroll
      for (int r = 0; r < 4; ++r) {
        int ic = min(ib + r, NTOK - 1);
        s[nt][r] = jv ? (s[nt][r] + bh[ic * NTOK + j]) : -3.0e38f;
      }
    }
    // row softmax: local over nt, then shfl_xor across the 16-lane column group
    float mx[4], sum[4], inv[4];
#pragma unroll
    for (int r = 0; r < 4; ++r) {
      float m = s[0][r];
#pragma unroll
      for (int nt = 1; nt < 7; ++nt) m = fmaxf(m, s[nt][r]);
      mx[r] = m;
    }
#pragma unroll
    for (int off = 1; off < 16; off <<= 1)
#pragma unroll
      for (int r = 0; r < 4; ++r) mx[r] = fmaxf(mx[r], __shfl_xor(mx[r], off));
#pragma unroll
    for (int r = 0; r < 4; ++r) sum[r] = 0.f;
#pragma unroll
    for (int nt = 0; nt < 7; ++nt)
#pragma unroll
      for (int r = 0; r < 4; ++r) {
        float e = __expf(s[nt][r] - mx[r]);
        s[nt][r] = e; sum[r] += e;
      }
#pragma unroll
    for (int off = 1; off < 16; off <<= 1)
#pragma unroll
      for (int r = 0; r < 4; ++r) sum[r] += __shfl_xor(sum[r], off);
#pragma unroll
    for (int r = 0; r < 4; ++r) inv[r] = 1.0f / sum[r];
    // write P (bf16) to own LDS tile in A-layout source form [i][j]
#pragma unroll
    for (int nt = 0; nt < 7; ++nt)
#pragma unroll
      for (int r = 0; r < 4; ++r)
        plh[(quad * 4 + r) * 136 + nt * 16 + lcol] = f2b(s[nt][r] * inv[r]);
    __syncthreads();
    // PV: A = P tile (K=128 padded with zeros), B = V^T
#pragma unroll
    for (int n2 = 0; n2 < 2; ++n2) {
      f32x4 acc = (f32x4){0.f, 0.f, 0.f, 0.f};
#pragma unroll
      for (int kp = 0; kp < 4; ++kp) {
        bf16x8 a = *(const bf16x8*)(plh + lcol * 136 + kp * 32 + quad * 8);
        bf16x8 b = *(const bf16x8*)(vth + (n2 * 16 + lcol) * 136 + kp * 32 + quad * 8);
        acc = __builtin_amdgcn_mfma_f32_16x16x32_bf16(a, b, acc, 0, 0, 0);
      }
      o[mt][n2] = acc;
    }
  }
  __syncthreads();   // all PV reads done before olds overlays vt/pl

  // ---- attn-out -> LDS [112][136], full 128 channels ----
  unsigned short* olds = smem;
#pragma unroll
  for (int mt = 0; mt < 7; ++mt)
#pragma unroll
    for (int n2 = 0; n2 < 2; ++n2)
#pragma unroll
      for (int r = 0; r < 4; ++r)
        olds[(mt * 16 + quad * 4 + r) * 136 + h * 32 + n2 * 16 + lcol] = f2b(o[mt][n2][r]);
  __syncthreads();

  // ---- proj + bias + residual scatter (reverse roll) ----
  const int bb = win >> 8, rW = win & 255;
  const int wd = rW >> 6, r2 = rW & 63, wh = r2 >> 3, ww = r2 & 7;
  for (int t2 = 0; t2 < 2; ++t2) {
    const int n = (h * 2 + t2) * 16 + lcol;
    bf16x8 bw[4];
#pragma unroll
    for (int kp = 0; kp < 4; ++kp)
      bw[kp] = *(const bf16x8*)(wp_t + (size_t)n * 128 + kp * 32 + quad * 8);
    const float bc = par[P_PROJB + n];
    for (int mt = 0; mt < 7; ++mt) {
      f32x4 acc = (f32x4){0.f, 0.f, 0.f, 0.f};
#pragma unroll
      for (int kp = 0; kp < 4; ++kp) {
        bf16x8 a = *(const bf16x8*)(olds + (mt * 16 + lcol) * 136 + kp * 32 + quad * 8);
        acc = __builtin_amdgcn_mfma_f32_16x16x32_bf16(a, bw[kp], acc, 0, 0, 0);
      }
#pragma unroll
      for (int r = 0; r < 4; ++r) {
        int m = mt * 16 + quad * 4 + r;
        if (m < NTOK) {
          int td = m / 49, r3 = m % 49, th = r3 / 7, tw = r3 % 7;
          int sd = (wd * 2 + td + 1) & 7;
          int sh = (wh * 7 + th + 3) % 56;
          int sw = (ww * 7 + tw + 3) % 56;
          size_t oidx = ((((size_t)bb * 8 + sd) * 56 + sh) * 56 + sw) * 128 + n;
          stf(out, oidx, f32, acc[r] + bc + ldf(x, oidx, f32));
        }
      }
    }
  }
}

// ---------------- K5: LN2 + MLP1(gelu) + MLP2 + residual (unchanged from r6) ----------------
__global__ __launch_bounds__(256) void mlp_kernel(
    const unsigned short* __restrict__ w1_t, const unsigned short* __restrict__ w2_t,
    const float* __restrict__ par, const int* __restrict__ flag,
    void* __restrict__ out) {
  __shared__ unsigned short lnt[32 * 136];
  __shared__ unsigned short hbuf[32 * 520];
  const int f32 = *flag;
  const int tid = threadIdx.x, wave = tid >> 6, lane = tid & 63;
  const int quad = lane >> 4, lcol = lane & 15;
  const int m0 = blockIdx.x * 32;

  for (int t = wave; t < 32; t += 4) {
    int c0 = lane * 2;
    float2 f = ldf2(out, (size_t)(m0 + t) * 128 + c0, f32);
    float s = f.x + f.y, ss = f.x * f.x + f.y * f.y;
#pragma unroll
    for (int off = 32; off >= 1; off >>= 1) { s += __shfl_xor(s, off); ss += __shfl_xor(ss, off); }
    float mu = s * (1.0f / 128.0f);
    float var = ss * (1.0f / 128.0f) - mu * mu;
    float rs = rsqrtf(var + 1e-5f);
    float y0 = (f.x - mu) * rs * par[P_LN2G + c0] + par[P_LN2B + c0];
    float y1 = (f.y - mu) * rs * par[P_LN2G + c0 + 1] + par[P_LN2B + c0 + 1];
    *(uint32_t*)(lnt + t * 136 + c0) = (uint32_t)f2b(y0) | ((uint32_t)f2b(y1) << 16);
  }
  __syncthreads();

  for (int p = 0; p < 8; ++p) {
    const int n = p * 64 + wave * 16 + lcol;
    bf16x8 bfr[4];
#pragma unroll
    for (int ks = 0; ks < 4; ++ks)
      bfr[ks] = *(const bf16x8*)(w1_t + (size_t)n * 128 + ks * 32 + quad * 8);
    const float bc = par[P_B1 + n];
#pragma unroll
    for (int mt = 0; mt < 2; ++mt) {
      f32x4 acc = (f32x4){0.f, 0.f, 0.f, 0.f};
#pragma unroll
      for (int ks = 0; ks < 4; ++ks) {
        bf16x8 a = *(const bf16x8*)(lnt + (mt * 16 + lcol) * 136 + ks * 32 + quad * 8);
        acc = __builtin_amdgcn_mfma_f32_16x16x32_bf16(a, bfr[ks], acc, 0, 0, 0);
      }
#pragma unroll
      for (int rr = 0; rr < 4; ++rr) {
        int m = mt * 16 + quad * 4 + rr;
        float v = acc[rr] + bc;
        v = 0.5f * v * (1.0f + erff(v * 0.70710678118654752f));
        hbuf[m * 520 + n] = f2b(v);
      }
    }
  }
  __syncthreads();

  f32x4 acc2[2][2];
#pragma unroll
  for (int a = 0; a < 2; ++a)
#pragma unroll
    for (int b = 0; b < 2; ++b) acc2[a][b] = (f32x4){0.f, 0.f, 0.f, 0.f};
#pragma unroll
  for (int np = 0; np < 2; ++np) {
    const int n = np * 64 + wave * 16 + lcol;
    for (int kp = 0; kp < 4; ++kp) {
      bf16x8 bfr[4];
#pragma unroll
      for (int ks = 0; ks < 4; ++ks)
        bfr[ks] = *(const bf16x8*)(w2_t + (size_t)n * 512 + kp * 128 + ks * 32 + quad * 8);
#pragma unroll
      for (int mt = 0; mt < 2; ++mt) {
#pragma unroll
        for (int ks = 0; ks < 4; ++ks) {
          bf16x8 a = *(const bf16x8*)(hbuf + (mt * 16 + lcol) * 520 + kp * 128 +
                                      ks * 32 + quad * 8);
          acc2[np][mt] = __builtin_amdgcn_mfma_f32_16x16x32_bf16(a, bfr[ks], acc2[np][mt], 0, 0, 0);
        }
      }
    }
  }
#pragma unroll
  for (int np = 0; np < 2; ++np) {
    const int n = np * 64 + wave * 16 + lcol;
    const float bc = par[P_B2 + n];
#pragma unroll
    for (int mt = 0; mt < 2; ++mt) {
#pragma unroll
      for (int rr = 0; rr < 4; ++rr) {
        size_t oi = (size_t)(m0 + mt * 16 + quad * 4 + rr) * 128 + n;
        stf(out, oi, f32, acc2[np][mt][rr] + bc + ldf(out, oi, f32));
      }
    }
  }
}

// ---------------- host launch ----------------
extern "C" void kernel_launch(void* const* d_in, const int* in_sizes, int n_in,
                              void* d_out, int out_size, void* d_ws, size_t ws_size,
                              hipStream_t stream) {
  const void* x      = d_in[0];
  const int*  rel    = (const int*)d_in[1];
  const void* rpb    = d_in[2];
  const void* qkv_w  = d_in[3];
  const void* qkv_b  = d_in[4];
  const void* proj_w = d_in[5];
  const void* proj_b = d_in[6];
  const void* ln1_g  = d_in[7];
  const void* ln1_b  = d_in[8];
  const void* ln2_g  = d_in[9];
  const void* ln2_b  = d_in[10];
  const void* w1     = d_in[11];
  const void* b1     = d_in[12];
  const void* w2     = d_in[13];
  const void* b2     = d_in[14];

  char* ws = (char*)d_ws;
  unsigned short* qg   = (unsigned short*)(ws + QG_OFF);
  unsigned short* kg   = (unsigned short*)(ws + KG_OFF);
  unsigned short* vg   = (unsigned short*)(ws + VG_OFF);
  float*          bias = (float*)(ws + BIAS_OFF);
  unsigned short* wq_t = (unsigned short*)(ws + WQ_OFF);
  unsigned short* wp_t = (unsigned short*)(ws + WP_OFF);
  unsigned short* w1_t = (unsigned short*)(ws + W1_OFF);
  unsigned short* w2_t = (unsigned short*)(ws + W2_OFF);
  float*          par  = (float*)(ws + PAR_OFF);
  int*            flag = (int*)(ws + FLAG_OFF);

  detect_kernel<<<1, 256, 0, stream>>>((const uint32_t*)x, flag);
  prep_kernel<<<775, 256, 0, stream>>>(qkv_w, proj_w, w1, w2, ln1_g, ln1_b, ln2_g,
                                       ln2_b, qkv_b, proj_b, b1, b2, flag,
                                       wq_t, wp_t, w1_t, w2_t, par);
  bias_kernel<<<(4 * BIAS_N + 255) / 256, 256, 0, stream>>>(rel, rpb, flag, bias);
  qkv_win_kernel<<<NWIN, 256, 0, stream>>>(x, flag, wq_t, par, qg, kg, vg);
  attn_fused_kernel<<<NWIN, 256, 0, stream>>>(qg, kg, vg, bias, wp_t, par, x, flag, d_out);
  mlp_kernel<<<100352 / 32, 256, 0, stream>>>(w1_t, w2_t, par, flag, d_out);
}